// Round 27
// baseline (379.211 us; speedup 1.0000x reference)
//
#include <hip/hip_runtime.h>
#include <math.h>

namespace {
constexpr int Bn    = 64;
constexpr int CIN   = 320;
constexpr int COUT  = 640;
constexpr int CIN_G = 32;   // 320/10
constexpr int COUT_G= 64;   // 640/10
constexpr int NH    = 4;
constexpr int Dd    = 160;
constexpr int ALLOCC= 16;
constexpr int Ss    = 1024; // 32*32
constexpr float ATT_SCALE = 0.0395284707521047f; // 640^-0.5

typedef float  f32x4  __attribute__((ext_vector_type(4)));
typedef int    i32x4  __attribute__((ext_vector_type(4)));

__device__ inline unsigned bf16rne(float f) {
    unsigned u = __float_as_uint(f);
    return (u + 0x7FFFu + ((u >> 16) & 1u)) >> 16;
}
__device__ inline unsigned packbf16(float a, float b) {
    return bf16rne(a) | (bf16rne(b) << 16);
}
}

// ---------------- K1: grouped conv3x3 MFMA — single-dyx wl (2 blk/CU) -------
// Identical to the R21/R23-proven kernel EXCEPT wl holds one dyx slice
// (4 KB, staged per iteration between barriers). LDS 111 -> 78 KB =>
// 2 blocks/CU; fragment math unchanged (wl offset just drops dyx*2048).
__global__ __launch_bounds__(512, 2) void conv_mfma_k(
    const float* __restrict__ x, const float* __restrict__ w1,
    const float* __restrict__ b1, float* __restrict__ out,
    double* __restrict__ statS, double* __restrict__ statS2) {
    __shared__ __align__(16) unsigned short xl[34 * 34 * 32];  // 73,984 B
    __shared__ __align__(16) unsigned short wl[64 * 32];       //  4,096 B

    int bg = blockIdx.x;
    int b = bg / 10, g = bg % 10;
    int tid = threadIdx.x;
    int wid = tid >> 6;
    int lane = tid & 63;
    int lc = lane & 15;
    int kl = (lane >> 4) * 8;

    unsigned* xl32 = (unsigned*)xl;
    unsigned* wl32 = (unsigned*)wl;

    for (int e = tid; e < 34 * 34 * 32 / 8; e += 512)
        *(i32x4*)&xl[e * 8] = i32x4{0, 0, 0, 0};
    __syncthreads();

    const float* xg = x + ((size_t)b * CIN + g * CIN_G) * Ss;
    for (int e = tid; e < 16 * 256; e += 512) {
        int icp = e & 15, q = e >> 4;
        int sp = q * 4;
        int r = (sp >> 5) + 1, c = (sp & 31) + 1;   // 4|32: quad stays in-row
        float4 f0 = *(const float4*)&xg[(size_t)(2 * icp) * Ss + sp];
        float4 f1 = *(const float4*)&xg[(size_t)(2 * icp + 1) * Ss + sp];
        unsigned base = (r * 34 + c) * 16 + icp;
        xl32[base]      = packbf16(f0.x, f1.x);
        xl32[base + 16] = packbf16(f0.y, f1.y);
        xl32[base + 32] = packbf16(f0.z, f1.z);
        xl32[base + 48] = packbf16(f0.w, f1.w);
    }
    __syncthreads();

    const float* wg = w1 + (size_t)(g * COUT_G) * (CIN_G * 9);

    f32x4 acc[4][8];
    #pragma unroll
    for (int mt = 0; mt < 4; ++mt)
        #pragma unroll
        for (int nt = 0; nt < 8; ++nt) acc[mt][nt] = f32x4{0.f, 0.f, 0.f, 0.f};

    for (int dyx = 0; dyx < 9; ++dyx) {
        // ---- stage this dyx's W slice (same expression, dyx fixed) ----
        for (int e = tid; e < 64 * 16; e += 512) {
            int icp = e & 15, oc = e >> 4;
            float f0 = wg[oc * 288 + (2 * icp) * 9 + dyx];
            float f1 = wg[oc * 288 + (2 * icp + 1) * 9 + dyx];
            wl32[oc * 16 + icp] = packbf16(f0, f1);
        }
        __syncthreads();

        int dy = dyx / 3, dx = dyx % 3;
        const unsigned short* wbase = wl + lc * 32 + kl;
        i32x4 af[4];
        #pragma unroll
        for (int mt = 0; mt < 4; ++mt)
            af[mt] = *(const i32x4*)(wbase + mt * 512);

        const unsigned short* xbase = xl + (dy * 34 + dx + lc) * 32 + kl
                                         + wid * 4 * 1088;
        #pragma unroll
        for (int nt = 0; nt < 8; ++nt) {
            i32x4 bf = *(const i32x4*)(xbase + (nt >> 1) * 1088 + (nt & 1) * 512);
            #pragma unroll
            for (int mt = 0; mt < 4; ++mt)
                asm("v_mfma_f32_16x16x32_bf16 %0, %1, %2, %0"
                    : "+v"(acc[mt][nt]) : "v"(af[mt]), "v"(bf));
        }
        __syncthreads();   // drain reads before next stage overwrites wl
    }

    #pragma unroll
    for (int mt = 0; mt < 4; ++mt) {
        #pragma unroll
        for (int r = 0; r < 4; ++r) {
            int ocg = mt * 16 + (lane >> 4) * 4 + r;
            float bias = b1[g * COUT_G + ocg];
            float ps = 0.f, ps2 = 0.f;
            float* orow = out + ((size_t)b * COUT + g * COUT_G + ocg) * Ss
                              + wid * 128 + lc;
            #pragma unroll
            for (int nt = 0; nt < 8; ++nt) {
                float v = acc[mt][nt][r] + bias;
                orow[nt * 16] = v;
                ps += v; ps2 += v * v;
            }
            #pragma unroll
            for (int m = 8; m; m >>= 1) {
                ps  += __shfl_xor(ps,  m, 16);
                ps2 += __shfl_xor(ps2, m, 16);
            }
            if (lc == 0) {
                atomicAdd(&statS[g * COUT_G + ocg],  (double)ps);
                atomicAdd(&statS2[g * COUT_G + ocg], (double)ps2);
            }
        }
    }
}

// ---------------- K2: finalize BN scale/shift ----------------
__global__ __launch_bounds__(256) void finalize_k(
    const double* __restrict__ statS, const double* __restrict__ statS2,
    const float* __restrict__ gamma, const float* __restrict__ beta,
    float* __restrict__ scaleC, float* __restrict__ shiftC) {
    int c = blockIdx.x * 256 + threadIdx.x;
    if (c >= COUT) return;
    double N = (double)Bn * Ss;
    double mean = statS[c] / N;
    double var  = statS2[c] / N - mean * mean;
    float sc = gamma[c] * rsqrtf((float)(var + 1e-5));
    scaleC[c] = sc;
    shiftC[c] = beta[c] - (float)mean * sc;
}

// ---------------- K4 v14: paired octets; q stored bf16, k/v fp32 (R23) ------
__global__ __launch_bounds__(256) void qkv_k(
    const float* __restrict__ conv, const float* __restrict__ wqkv,
    const float* __restrict__ scaleC, const float* __restrict__ shiftC,
    const int* __restrict__ y,
    unsigned short* __restrict__ qb16, float* __restrict__ ksub,
    float* __restrict__ vsub) {
    int l = blockIdx.x;
    int xcd = l & 7;
    int t2 = l >> 3;
    int m = t2 % 48;
    int b = (t2 / 48) * 8 + xcd;
    int tid = threadIdx.x;
    int yv = __builtin_amdgcn_readfirstlane(y[b]);

    int r0a, r0b;
    unsigned short *qA = nullptr, *qB = nullptr;
    float *fA = nullptr, *fB = nullptr;
    if (m < 40) {                 // both octets q
        r0a = (2 * m) * 8;
        r0b = (2 * m + 1) * 8;
        int ha = r0a / Dd, da = r0a - ha * Dd;
        int hb = r0b / Dd, db = r0b - hb * Dd;
        qA = qb16 + ((size_t)(b * NH + ha) * Dd + da) * Ss;
        qB = qb16 + ((size_t)(b * NH + hb) * Dd + db) * Ss;
    } else {                      // k/v pair (j0 = 0 and 8 of one head)
        int o = 2 * m;            // 80..94 even
        if (o < 88) {
            int t = o - 80;
            int h = t >> 1;
            r0a = COUT + h * Dd + yv * ALLOCC;
            r0b = r0a + 8;
            fA = ksub + ((size_t)(b * NH + h) * ALLOCC + 0) * Ss;
            fB = ksub + ((size_t)(b * NH + h) * ALLOCC + 8) * Ss;
        } else {
            int t = o - 88;
            int h = t >> 1;
            r0a = 2 * COUT + h * Dd + yv * ALLOCC;
            r0b = r0a + 8;
            fA = vsub + ((size_t)(b * NH + h) * ALLOCC + 0) * Ss;
            fB = vsub + ((size_t)(b * NH + h) * ALLOCC + 8) * Ss;
        }
    }
    int g = r0a / 192;                       // same for both octets
    const float* cb = conv + ((size_t)b * COUT + g * COUT_G) * Ss + tid;
    const float* wrA = wqkv + (size_t)r0a * COUT_G;   // block-uniform
    const float* wrB = wqkv + (size_t)r0b * COUT_G;
    const float* sC = scaleC + g * COUT_G;
    const float* sH = shiftC + g * COUT_G;

    float a[4][16];
    #pragma unroll
    for (int st = 0; st < 4; ++st)
        #pragma unroll
        for (int r = 0; r < 16; ++r) a[st][r] = 0.f;

    #pragma unroll 4
    for (int ic = 0; ic < 64; ++ic) {
        float sc = sC[ic], sh = sH[ic];
        float wA0 = wrA[0 * 64 + ic], wA1 = wrA[1 * 64 + ic];
        float wA2 = wrA[2 * 64 + ic], wA3 = wrA[3 * 64 + ic];
        float wA4 = wrA[4 * 64 + ic], wA5 = wrA[5 * 64 + ic];
        float wA6 = wrA[6 * 64 + ic], wA7 = wrA[7 * 64 + ic];
        float wB0 = wrB[0 * 64 + ic], wB1 = wrB[1 * 64 + ic];
        float wB2 = wrB[2 * 64 + ic], wB3 = wrB[3 * 64 + ic];
        float wB4 = wrB[4 * 64 + ic], wB5 = wrB[5 * 64 + ic];
        float wB6 = wrB[6 * 64 + ic], wB7 = wrB[7 * 64 + ic];
        #pragma unroll
        for (int st = 0; st < 4; ++st) {
            float v = fmaxf(fmaf(cb[(size_t)ic * Ss + st * 256], sc, sh), 0.f);
            a[st][0]  = fmaf(wA0, v, a[st][0]);
            a[st][1]  = fmaf(wA1, v, a[st][1]);
            a[st][2]  = fmaf(wA2, v, a[st][2]);
            a[st][3]  = fmaf(wA3, v, a[st][3]);
            a[st][4]  = fmaf(wA4, v, a[st][4]);
            a[st][5]  = fmaf(wA5, v, a[st][5]);
            a[st][6]  = fmaf(wA6, v, a[st][6]);
            a[st][7]  = fmaf(wA7, v, a[st][7]);
            a[st][8]  = fmaf(wB0, v, a[st][8]);
            a[st][9]  = fmaf(wB1, v, a[st][9]);
            a[st][10] = fmaf(wB2, v, a[st][10]);
            a[st][11] = fmaf(wB3, v, a[st][11]);
            a[st][12] = fmaf(wB4, v, a[st][12]);
            a[st][13] = fmaf(wB5, v, a[st][13]);
            a[st][14] = fmaf(wB6, v, a[st][14]);
            a[st][15] = fmaf(wB7, v, a[st][15]);
        }
    }

    if (m < 40) {
        #pragma unroll
        for (int r = 0; r < 8; ++r)
            #pragma unroll
            for (int st = 0; st < 4; ++st) {
                qA[(size_t)r * Ss + st * 256 + tid] = (unsigned short)bf16rne(a[st][r]);
                qB[(size_t)r * Ss + st * 256 + tid] = (unsigned short)bf16rne(a[st][8 + r]);
            }
    } else {
        #pragma unroll
        for (int r = 0; r < 8; ++r)
            #pragma unroll
            for (int st = 0; st < 4; ++st) {
                fA[(size_t)r * Ss + st * 256 + tid] = a[st][r];
                fB[(size_t)r * Ss + st * 256 + tid] = a[st][8 + r];
            }
    }
}

// ---------------- K5a: QK^T partials (q bf16, k fp32) -----------------------
__global__ __launch_bounds__(256) void qk_k(
    const unsigned short* __restrict__ q, const float* __restrict__ ksub,
    float* __restrict__ partial) {
    __shared__ float qv[160 * 68];
    __shared__ float klds[16 * 68];

    int bh = blockIdx.x, sq = blockIdx.y;
    int tid = threadIdx.x;
    int jt = tid & 15;
    int ig = tid >> 4;

    const unsigned short* qb = q + (size_t)bh * Dd * Ss + sq * 256;
    const float* kb = ksub + (size_t)bh * ALLOCC * Ss + sq * 256;

    float acc[10];
    #pragma unroll
    for (int r = 0; r < 10; ++r) acc[r] = 0.f;

    for (int s0 = 0; s0 < 256; s0 += 64) {
        for (int e = tid; e < 160 * 32; e += 256) {   // u32 units (2 bf16)
            int i = e >> 5, p = e & 31;
            unsigned u = *(const unsigned*)&qb[(size_t)i * Ss + s0 + 2 * p];
            qv[i * 68 + 2 * p]     = __uint_as_float(u << 16);
            qv[i * 68 + 2 * p + 1] = __uint_as_float(u & 0xffff0000u);
        }
        for (int e = tid; e < 16 * 64; e += 256) {
            int j = e >> 6, s2 = e & 63;
            klds[j * 68 + s2] = kb[(size_t)j * Ss + s0 + s2];
        }
        __syncthreads();
        for (int s2 = 0; s2 < 64; s2 += 4) {
            float4 kq = *(const float4*)&klds[jt * 68 + s2];
            #pragma unroll
            for (int r = 0; r < 10; ++r) {
                int i = ig + 16 * r;
                float4 qq = *(const float4*)&qv[i * 68 + s2];
                acc[r] += qq.x * kq.x + qq.y * kq.y + qq.z * kq.z + qq.w * kq.w;
            }
        }
        __syncthreads();
    }
    float* pp = partial + ((size_t)(bh * 4 + sq)) * (Dd * 16);
    #pragma unroll
    for (int r = 0; r < 10; ++r)
        pp[(ig + 16 * r) * 16 + jt] = acc[r];
}

// ---------------- K5b: reduce + masked softmax -> attn, P (zero fused) ------
__global__ __launch_bounds__(256) void sm_k(
    const float* __restrict__ partial, const int* __restrict__ y,
    float* __restrict__ attn, float* __restrict__ P) {
    int bh = blockIdx.x;
    int b = bh >> 2;
    int tid = threadIdx.x;
    int jt = tid & 15;
    int ig = tid >> 4;
    int ycol = y[b] * ALLOCC;

    // zero this block's 160x160 attn slab (fused former zerof_k)
    float* ab = attn + (size_t)bh * Dd * Dd;
    float4 z = {0.f, 0.f, 0.f, 0.f};
    for (int e = tid; e < Dd * Dd / 4; e += 256)
        ((float4*)ab)[e] = z;
    __syncthreads();

    const float* pb = partial + (size_t)bh * 4 * (Dd * 16);
    #pragma unroll
    for (int r = 0; r < 10; ++r) {
        int i = ig + 16 * r;
        const float* pp = pb + i * 16 + jt;
        float d = (pp[0] + pp[Dd * 16] + pp[2 * Dd * 16] + pp[3 * Dd * 16]) * ATT_SCALE;
        float mx = d;
        #pragma unroll
        for (int m = 8; m; m >>= 1) mx = fmaxf(mx, __shfl_xor(mx, m, 16));
        float e = __expf(d - mx);
        float sum = e;
        #pragma unroll
        for (int m = 8; m; m >>= 1) sum += __shfl_xor(sum, m, 16);
        float p = e / sum;
        ab[(size_t)i * Dd + ycol + jt] = p;
        P[(size_t)bh * (Dd * 16) + i * 16 + jt] = p;
    }
}

// ---------------- K5c: PV (grid bh x 4 s-quarters) --------------------------
__global__ __launch_bounds__(256) void pv_k(
    const float* __restrict__ P, const float* __restrict__ vsub,
    float* __restrict__ o) {
    __shared__ float plds[160 * 16];
    __shared__ float vlds[16][256];

    int bh = blockIdx.x, sq = blockIdx.y;
    int b = bh >> 2, h = bh & 3;
    int tid = threadIdx.x;

    for (int e = tid; e < 160 * 16; e += 256)
        plds[e] = P[(size_t)bh * (Dd * 16) + e];
    #pragma unroll
    for (int j = 0; j < 16; ++j)
        vlds[j][tid] = vsub[((size_t)bh * ALLOCC + j) * Ss + sq * 256 + tid];
    __syncthreads();

    float vr[16];
    #pragma unroll
    for (int j = 0; j < 16; ++j) vr[j] = vlds[j][tid];

    float* obp = o + ((size_t)b * COUT + h * Dd) * Ss + sq * 256 + tid;
    for (int i = 0; i < Dd; ++i) {
        const float4* p4 = (const float4*)&plds[i * 16];
        float a = 0.f;
        #pragma unroll
        for (int j4 = 0; j4 < 4; ++j4) {
            float4 pv = p4[j4];
            a += pv.x * vr[j4 * 4 + 0] + pv.y * vr[j4 * 4 + 1]
               + pv.z * vr[j4 * 4 + 2] + pv.w * vr[j4 * 4 + 3];
        }
        obp[(size_t)i * Ss] = a;
    }
}

extern "C" void kernel_launch(void* const* d_in, const int* in_sizes, int n_in,
                              void* d_out, int out_size, void* d_ws, size_t ws_size,
                              hipStream_t stream) {
    const float* x     = (const float*)d_in[0];
    const int*   y     = (const int*)  d_in[1];
    const float* w1    = (const float*)d_in[2];
    const float* b1    = (const float*)d_in[3];
    const float* gamma = (const float*)d_in[4];
    const float* beta  = (const float*)d_in[5];
    const float* wqkv  = (const float*)d_in[6];

    float* o    = (float*)d_out;
    float* attn = o + (size_t)Bn * COUT * Ss;

    float* ws     = (float*)d_ws;
    float* conv   = ws;
    unsigned short* qb16 = (unsigned short*)(conv + (size_t)Bn * COUT * Ss);
    float* kf     = (float*)(qb16 + (size_t)Bn * NH * Dd * Ss);
    float* vf     = kf   + (size_t)Bn * NH * ALLOCC * Ss;
    float* part   = vf   + (size_t)Bn * NH * ALLOCC * Ss;       // 256*4*2560 f
    float* Pbuf   = part + (size_t)Bn * NH * 4 * Dd * ALLOCC;   // 256*2560 f
    float* scaleC = Pbuf + (size_t)Bn * NH * Dd * ALLOCC;
    float* shiftC = scaleC + COUT;
    double* statS  = (double*)(shiftC + COUT);
    double* statS2 = statS + COUT;

    (void)hipMemsetAsync(statS, 0, 2 * COUT * sizeof(double), stream);
    conv_mfma_k<<<Bn * 10, 512, 0, stream>>>(x, w1, b1, conv, statS, statS2);
    finalize_k<<<(COUT + 255) / 256, 256, 0, stream>>>(statS, statS2, gamma, beta, scaleC, shiftC);
    qkv_k<<<48 * Bn, 256, 0, stream>>>(conv, wqkv, scaleC, shiftC, y, qb16, kf, vf);
    qk_k<<<dim3(Bn * NH, 4), 256, 0, stream>>>(qb16, kf, part);
    sm_k<<<Bn * NH, 256, 0, stream>>>(part, y, attn, Pbuf);
    pv_k<<<dim3(Bn * NH, 4), 256, 0, stream>>>(Pbuf, vf, o);
}

// Round 28
// 367.882 us; speedup vs baseline: 1.0308x; 1.0308x over previous
//
#include <hip/hip_runtime.h>
#include <math.h>

namespace {
constexpr int Bn    = 64;
constexpr int CIN   = 320;
constexpr int COUT  = 640;
constexpr int CIN_G = 32;   // 320/10
constexpr int COUT_G= 64;   // 640/10
constexpr int NH    = 4;
constexpr int Dd    = 160;
constexpr int ALLOCC= 16;
constexpr int Ss    = 1024; // 32*32
constexpr float ATT_SCALE = 0.0395284707521047f; // 640^-0.5

typedef float  f32x4  __attribute__((ext_vector_type(4)));
typedef int    i32x4  __attribute__((ext_vector_type(4)));

__device__ inline unsigned bf16rne(float f) {
    unsigned u = __float_as_uint(f);
    return (u + 0x7FFFu + ((u >> 16) & 1u)) >> 16;
}
__device__ inline unsigned packbf16(float a, float b) {
    return bf16rne(a) | (bf16rne(b) << 16);
}
}

// ---------------- K1: grouped conv3x3 MFMA (R21/R23/R26 proven, exact) ------
__global__ __launch_bounds__(512, 2) void conv_mfma_k(
    const float* __restrict__ x, const float* __restrict__ w1,
    const float* __restrict__ b1, float* __restrict__ out,
    double* __restrict__ statS, double* __restrict__ statS2) {
    __shared__ __align__(16) unsigned short xl[34 * 34 * 32];
    __shared__ __align__(16) unsigned short wl[9 * 64 * 32];

    int bg = blockIdx.x;
    int b = bg / 10, g = bg % 10;
    int tid = threadIdx.x;
    int wid = tid >> 6;
    int lane = tid & 63;
    int lc = lane & 15;
    int kl = (lane >> 4) * 8;

    unsigned* xl32 = (unsigned*)xl;
    unsigned* wl32 = (unsigned*)wl;

    for (int e = tid; e < 34 * 34 * 32 / 8; e += 512)
        *(i32x4*)&xl[e * 8] = i32x4{0, 0, 0, 0};
    __syncthreads();

    const float* xg = x + ((size_t)b * CIN + g * CIN_G) * Ss;
    for (int e = tid; e < 16 * 256; e += 512) {
        int icp = e & 15, q = e >> 4;
        int sp = q * 4;
        int r = (sp >> 5) + 1, c = (sp & 31) + 1;   // 4|32: quad stays in-row
        float4 f0 = *(const float4*)&xg[(size_t)(2 * icp) * Ss + sp];
        float4 f1 = *(const float4*)&xg[(size_t)(2 * icp + 1) * Ss + sp];
        unsigned base = (r * 34 + c) * 16 + icp;
        xl32[base]      = packbf16(f0.x, f1.x);
        xl32[base + 16] = packbf16(f0.y, f1.y);
        xl32[base + 32] = packbf16(f0.z, f1.z);
        xl32[base + 48] = packbf16(f0.w, f1.w);
    }
    const float* wg = w1 + (size_t)(g * COUT_G) * (CIN_G * 9);
    for (int e = tid; e < 9 * 64 * 16; e += 512) {
        int icp = e & 15, oc = (e >> 4) & 63, dyx = e >> 10;
        float f0 = wg[oc * 288 + (2 * icp) * 9 + dyx];
        float f1 = wg[oc * 288 + (2 * icp + 1) * 9 + dyx];
        wl32[(dyx * 64 + oc) * 16 + icp] = packbf16(f0, f1);
    }
    __syncthreads();

    f32x4 acc[4][8];
    #pragma unroll
    for (int mt = 0; mt < 4; ++mt)
        #pragma unroll
        for (int nt = 0; nt < 8; ++nt) acc[mt][nt] = f32x4{0.f, 0.f, 0.f, 0.f};

    for (int dyx = 0; dyx < 9; ++dyx) {
        int dy = dyx / 3, dx = dyx % 3;
        const unsigned short* wbase = wl + dyx * 2048 + lc * 32 + kl;
        i32x4 af[4];
        #pragma unroll
        for (int mt = 0; mt < 4; ++mt)
            af[mt] = *(const i32x4*)(wbase + mt * 512);

        const unsigned short* xbase = xl + (dy * 34 + dx + lc) * 32 + kl
                                         + wid * 4 * 1088;
        #pragma unroll
        for (int nt = 0; nt < 8; ++nt) {
            i32x4 bf = *(const i32x4*)(xbase + (nt >> 1) * 1088 + (nt & 1) * 512);
            #pragma unroll
            for (int mt = 0; mt < 4; ++mt)
                asm("v_mfma_f32_16x16x32_bf16 %0, %1, %2, %0"
                    : "+v"(acc[mt][nt]) : "v"(af[mt]), "v"(bf));
        }
    }

    #pragma unroll
    for (int mt = 0; mt < 4; ++mt) {
        #pragma unroll
        for (int r = 0; r < 4; ++r) {
            int ocg = mt * 16 + (lane >> 4) * 4 + r;
            float bias = b1[g * COUT_G + ocg];
            float ps = 0.f, ps2 = 0.f;
            float* orow = out + ((size_t)b * COUT + g * COUT_G + ocg) * Ss
                              + wid * 128 + lc;
            #pragma unroll
            for (int nt = 0; nt < 8; ++nt) {
                float v = acc[mt][nt][r] + bias;
                orow[nt * 16] = v;
                ps += v; ps2 += v * v;
            }
            #pragma unroll
            for (int m = 8; m; m >>= 1) {
                ps  += __shfl_xor(ps,  m, 16);
                ps2 += __shfl_xor(ps2, m, 16);
            }
            if (lc == 0) {
                atomicAdd(&statS[g * COUT_G + ocg],  (double)ps);
                atomicAdd(&statS2[g * COUT_G + ocg], (double)ps2);
            }
        }
    }
}

// ---------------- K2: finalize BN scale/shift ----------------
__global__ __launch_bounds__(256) void finalize_k(
    const double* __restrict__ statS, const double* __restrict__ statS2,
    const float* __restrict__ gamma, const float* __restrict__ beta,
    float* __restrict__ scaleC, float* __restrict__ shiftC) {
    int c = blockIdx.x * 256 + threadIdx.x;
    if (c >= COUT) return;
    double N = (double)Bn * Ss;
    double mean = statS[c] / N;
    double var  = statS2[c] / N - mean * mean;
    float sc = gamma[c] * rsqrtf((float)(var + 1e-5));
    scaleC[c] = sc;
    shiftC[c] = beta[c] - (float)mean * sc;
}

// ---------------- K4 v14: paired octets; q stored bf16, k/v fp32 (R23) ------
__global__ __launch_bounds__(256) void qkv_k(
    const float* __restrict__ conv, const float* __restrict__ wqkv,
    const float* __restrict__ scaleC, const float* __restrict__ shiftC,
    const int* __restrict__ y,
    unsigned short* __restrict__ qb16, float* __restrict__ ksub,
    float* __restrict__ vsub) {
    int l = blockIdx.x;
    int xcd = l & 7;
    int t2 = l >> 3;
    int m = t2 % 48;
    int b = (t2 / 48) * 8 + xcd;
    int tid = threadIdx.x;
    int yv = __builtin_amdgcn_readfirstlane(y[b]);

    int r0a, r0b;
    unsigned short *qA = nullptr, *qB = nullptr;
    float *fA = nullptr, *fB = nullptr;
    if (m < 40) {                 // both octets q
        r0a = (2 * m) * 8;
        r0b = (2 * m + 1) * 8;
        int ha = r0a / Dd, da = r0a - ha * Dd;
        int hb = r0b / Dd, db = r0b - hb * Dd;
        qA = qb16 + ((size_t)(b * NH + ha) * Dd + da) * Ss;
        qB = qb16 + ((size_t)(b * NH + hb) * Dd + db) * Ss;
    } else {                      // k/v pair (j0 = 0 and 8 of one head)
        int o = 2 * m;            // 80..94 even
        if (o < 88) {
            int t = o - 80;
            int h = t >> 1;
            r0a = COUT + h * Dd + yv * ALLOCC;
            r0b = r0a + 8;
            fA = ksub + ((size_t)(b * NH + h) * ALLOCC + 0) * Ss;
            fB = ksub + ((size_t)(b * NH + h) * ALLOCC + 8) * Ss;
        } else {
            int t = o - 88;
            int h = t >> 1;
            r0a = 2 * COUT + h * Dd + yv * ALLOCC;
            r0b = r0a + 8;
            fA = vsub + ((size_t)(b * NH + h) * ALLOCC + 0) * Ss;
            fB = vsub + ((size_t)(b * NH + h) * ALLOCC + 8) * Ss;
        }
    }
    int g = r0a / 192;                       // same for both octets
    const float* cb = conv + ((size_t)b * COUT + g * COUT_G) * Ss + tid;
    const float* wrA = wqkv + (size_t)r0a * COUT_G;   // block-uniform
    const float* wrB = wqkv + (size_t)r0b * COUT_G;
    const float* sC = scaleC + g * COUT_G;
    const float* sH = shiftC + g * COUT_G;

    float a[4][16];
    #pragma unroll
    for (int st = 0; st < 4; ++st)
        #pragma unroll
        for (int r = 0; r < 16; ++r) a[st][r] = 0.f;

    #pragma unroll 4
    for (int ic = 0; ic < 64; ++ic) {
        float sc = sC[ic], sh = sH[ic];
        float wA0 = wrA[0 * 64 + ic], wA1 = wrA[1 * 64 + ic];
        float wA2 = wrA[2 * 64 + ic], wA3 = wrA[3 * 64 + ic];
        float wA4 = wrA[4 * 64 + ic], wA5 = wrA[5 * 64 + ic];
        float wA6 = wrA[6 * 64 + ic], wA7 = wrA[7 * 64 + ic];
        float wB0 = wrB[0 * 64 + ic], wB1 = wrB[1 * 64 + ic];
        float wB2 = wrB[2 * 64 + ic], wB3 = wrB[3 * 64 + ic];
        float wB4 = wrB[4 * 64 + ic], wB5 = wrB[5 * 64 + ic];
        float wB6 = wrB[6 * 64 + ic], wB7 = wrB[7 * 64 + ic];
        #pragma unroll
        for (int st = 0; st < 4; ++st) {
            float v = fmaxf(fmaf(cb[(size_t)ic * Ss + st * 256], sc, sh), 0.f);
            a[st][0]  = fmaf(wA0, v, a[st][0]);
            a[st][1]  = fmaf(wA1, v, a[st][1]);
            a[st][2]  = fmaf(wA2, v, a[st][2]);
            a[st][3]  = fmaf(wA3, v, a[st][3]);
            a[st][4]  = fmaf(wA4, v, a[st][4]);
            a[st][5]  = fmaf(wA5, v, a[st][5]);
            a[st][6]  = fmaf(wA6, v, a[st][6]);
            a[st][7]  = fmaf(wA7, v, a[st][7]);
            a[st][8]  = fmaf(wB0, v, a[st][8]);
            a[st][9]  = fmaf(wB1, v, a[st][9]);
            a[st][10] = fmaf(wB2, v, a[st][10]);
            a[st][11] = fmaf(wB3, v, a[st][11]);
            a[st][12] = fmaf(wB4, v, a[st][12]);
            a[st][13] = fmaf(wB5, v, a[st][13]);
            a[st][14] = fmaf(wB6, v, a[st][14]);
            a[st][15] = fmaf(wB7, v, a[st][15]);
        }
    }

    if (m < 40) {
        #pragma unroll
        for (int r = 0; r < 8; ++r)
            #pragma unroll
            for (int st = 0; st < 4; ++st) {
                qA[(size_t)r * Ss + st * 256 + tid] = (unsigned short)bf16rne(a[st][r]);
                qB[(size_t)r * Ss + st * 256 + tid] = (unsigned short)bf16rne(a[st][8 + r]);
            }
    } else {
        #pragma unroll
        for (int r = 0; r < 8; ++r)
            #pragma unroll
            for (int st = 0; st < 4; ++st) {
                fA[(size_t)r * Ss + st * 256 + tid] = a[st][r];
                fB[(size_t)r * Ss + st * 256 + tid] = a[st][8 + r];
            }
    }
}

// ---------------- K5a: QK^T partials (q bf16, k fp32) -----------------------
__global__ __launch_bounds__(256) void qk_k(
    const unsigned short* __restrict__ q, const float* __restrict__ ksub,
    float* __restrict__ partial) {
    __shared__ float qv[160 * 68];
    __shared__ float klds[16 * 68];

    int bh = blockIdx.x, sq = blockIdx.y;
    int tid = threadIdx.x;
    int jt = tid & 15;
    int ig = tid >> 4;

    const unsigned short* qb = q + (size_t)bh * Dd * Ss + sq * 256;
    const float* kb = ksub + (size_t)bh * ALLOCC * Ss + sq * 256;

    float acc[10];
    #pragma unroll
    for (int r = 0; r < 10; ++r) acc[r] = 0.f;

    for (int s0 = 0; s0 < 256; s0 += 64) {
        for (int e = tid; e < 160 * 32; e += 256) {   // u32 units (2 bf16)
            int i = e >> 5, p = e & 31;
            unsigned u = *(const unsigned*)&qb[(size_t)i * Ss + s0 + 2 * p];
            qv[i * 68 + 2 * p]     = __uint_as_float(u << 16);
            qv[i * 68 + 2 * p + 1] = __uint_as_float(u & 0xffff0000u);
        }
        for (int e = tid; e < 16 * 64; e += 256) {
            int j = e >> 6, s2 = e & 63;
            klds[j * 68 + s2] = kb[(size_t)j * Ss + s0 + s2];
        }
        __syncthreads();
        for (int s2 = 0; s2 < 64; s2 += 4) {
            float4 kq = *(const float4*)&klds[jt * 68 + s2];
            #pragma unroll
            for (int r = 0; r < 10; ++r) {
                int i = ig + 16 * r;
                float4 qq = *(const float4*)&qv[i * 68 + s2];
                acc[r] += qq.x * kq.x + qq.y * kq.y + qq.z * kq.z + qq.w * kq.w;
            }
        }
        __syncthreads();
    }
    float* pp = partial + ((size_t)(bh * 4 + sq)) * (Dd * 16);
    #pragma unroll
    for (int r = 0; r < 10; ++r)
        pp[(ig + 16 * r) * 16 + jt] = acc[r];
}

// ---------------- K5b: reduce + masked softmax -> attn, P (zero fused) ------
__global__ __launch_bounds__(256) void sm_k(
    const float* __restrict__ partial, const int* __restrict__ y,
    float* __restrict__ attn, float* __restrict__ P) {
    int bh = blockIdx.x;
    int b = bh >> 2;
    int tid = threadIdx.x;
    int jt = tid & 15;
    int ig = tid >> 4;
    int ycol = y[b] * ALLOCC;

    // zero this block's 160x160 attn slab (fused former zerof_k)
    float* ab = attn + (size_t)bh * Dd * Dd;
    float4 z = {0.f, 0.f, 0.f, 0.f};
    for (int e = tid; e < Dd * Dd / 4; e += 256)
        ((float4*)ab)[e] = z;
    __syncthreads();

    const float* pb = partial + (size_t)bh * 4 * (Dd * 16);
    #pragma unroll
    for (int r = 0; r < 10; ++r) {
        int i = ig + 16 * r;
        const float* pp = pb + i * 16 + jt;
        float d = (pp[0] + pp[Dd * 16] + pp[2 * Dd * 16] + pp[3 * Dd * 16]) * ATT_SCALE;
        float mx = d;
        #pragma unroll
        for (int m = 8; m; m >>= 1) mx = fmaxf(mx, __shfl_xor(mx, m, 16));
        float e = __expf(d - mx);
        float sum = e;
        #pragma unroll
        for (int m = 8; m; m >>= 1) sum += __shfl_xor(sum, m, 16);
        float p = e / sum;
        ab[(size_t)i * Dd + ycol + jt] = p;
        P[(size_t)bh * (Dd * 16) + i * 16 + jt] = p;
    }
}

// ---------------- K5c: PV (grid bh x 4 s-quarters) --------------------------
__global__ __launch_bounds__(256) void pv_k(
    const float* __restrict__ P, const float* __restrict__ vsub,
    float* __restrict__ o) {
    __shared__ float plds[160 * 16];
    __shared__ float vlds[16][256];

    int bh = blockIdx.x, sq = blockIdx.y;
    int b = bh >> 2, h = bh & 3;
    int tid = threadIdx.x;

    for (int e = tid; e < 160 * 16; e += 256)
        plds[e] = P[(size_t)bh * (Dd * 16) + e];
    #pragma unroll
    for (int j = 0; j < 16; ++j)
        vlds[j][tid] = vsub[((size_t)bh * ALLOCC + j) * Ss + sq * 256 + tid];
    __syncthreads();

    float vr[16];
    #pragma unroll
    for (int j = 0; j < 16; ++j) vr[j] = vlds[j][tid];

    float* obp = o + ((size_t)b * COUT + h * Dd) * Ss + sq * 256 + tid;
    for (int i = 0; i < Dd; ++i) {
        const float4* p4 = (const float4*)&plds[i * 16];
        float a = 0.f;
        #pragma unroll
        for (int j4 = 0; j4 < 4; ++j4) {
            float4 pv = p4[j4];
            a += pv.x * vr[j4 * 4 + 0] + pv.y * vr[j4 * 4 + 1]
               + pv.z * vr[j4 * 4 + 2] + pv.w * vr[j4 * 4 + 3];
        }
        obp[(size_t)i * Ss] = a;
    }
}

extern "C" void kernel_launch(void* const* d_in, const int* in_sizes, int n_in,
                              void* d_out, int out_size, void* d_ws, size_t ws_size,
                              hipStream_t stream) {
    const float* x     = (const float*)d_in[0];
    const int*   y     = (const int*)  d_in[1];
    const float* w1    = (const float*)d_in[2];
    const float* b1    = (const float*)d_in[3];
    const float* gamma = (const float*)d_in[4];
    const float* beta  = (const float*)d_in[5];
    const float* wqkv  = (const float*)d_in[6];

    float* o    = (float*)d_out;
    float* attn = o + (size_t)Bn * COUT * Ss;

    float* ws     = (float*)d_ws;
    float* conv   = ws;
    unsigned short* qb16 = (unsigned short*)(conv + (size_t)Bn * COUT * Ss);
    float* kf     = (float*)(qb16 + (size_t)Bn * NH * Dd * Ss);
    float* vf     = kf   + (size_t)Bn * NH * ALLOCC * Ss;
    float* part   = vf   + (size_t)Bn * NH * ALLOCC * Ss;       // 256*4*2560 f
    float* Pbuf   = part + (size_t)Bn * NH * 4 * Dd * ALLOCC;   // 256*2560 f
    float* scaleC = Pbuf + (size_t)Bn * NH * Dd * ALLOCC;
    float* shiftC = scaleC + COUT;
    double* statS  = (double*)(shiftC + COUT);
    double* statS2 = statS + COUT;

    (void)hipMemsetAsync(statS, 0, 2 * COUT * sizeof(double), stream);
    conv_mfma_k<<<Bn * 10, 512, 0, stream>>>(x, w1, b1, conv, statS, statS2);
    finalize_k<<<(COUT + 255) / 256, 256, 0, stream>>>(statS, statS2, gamma, beta, scaleC, shiftC);
    qkv_k<<<48 * Bn, 256, 0, stream>>>(conv, wqkv, scaleC, shiftC, y, qb16, kf, vf);
    qk_k<<<dim3(Bn * NH, 4), 256, 0, stream>>>(qb16, kf, part);
    sm_k<<<Bn * NH, 256, 0, stream>>>(part, y, attn, Pbuf);
    pv_k<<<dim3(Bn * NH, 4), 256, 0, stream>>>(Pbuf, vf, o);
}